// Round 2
// baseline (1615.292 us; speedup 1.0000x reference)
//
#include <hip/hip_runtime.h>
#include <math.h>

#define T_LEN 16384
#define H_DIM 1024
#define C_DIM 256

// ---------------- ws layout (float offsets) ----------------
// [0, 786432)       wt   : transposed weights (3, H, C)
// [786432, 802816)  alpha: (T)
// [802816, 819200)  fire_t (int)
// [819200, 835584)  wu1
// [835584, 851968)  wu2
// [851968, +8)      meta: nf (int), finflag (int)

// transpose conv_w (C,H,3) -> wt (3,H,C)  [coalesced writes]
__global__ __launch_bounds__(256) void kwt(const float* __restrict__ w,
                                           float* __restrict__ wt) {
  int idx = blockIdx.x * 256 + threadIdx.x;   // = h*256 + c
  int h = idx >> 8;
  int c = idx & 255;
  const float* s = w + ((size_t)c * H_DIM + h) * 3;
  float a0 = s[0], a1 = s[1], a2 = s[2];
  wt[((size_t)0 * H_DIM + h) * C_DIM + c] = a0;
  wt[((size_t)1 * H_DIM + h) * C_DIM + c] = a1;
  wt[((size_t)2 * H_DIM + h) * C_DIM + c] = a2;
}

// fused conv1d(K=3) + bias + LayerNorm + ReLU + linear + sigmoid -> alpha[T]
// grid 256 blocks, 64 t-rows per block, all 256 channels per block.
__global__ __launch_bounds__(256) void kconv(
    const float* __restrict__ x, const float* __restrict__ wt,
    const float* __restrict__ cb, const float* __restrict__ lng,
    const float* __restrict__ lnb, const float* __restrict__ lw,
    const float* __restrict__ lb, float* __restrict__ alpha)
{
  __shared__ float As[32][68];    // [k][row], padded (68: 16B-aligned, bank-rotating)
  __shared__ float Bs[32][260];   // [k][col], padded
  const int tid = threadIdx.x;
  const int t0 = blockIdx.x * 64;
  const int i = tid >> 5;        // 0..7  row group (rows 8i..8i+7)
  const int j = tid & 31;        // 0..31 col group (cols 4j..4j+3 and 128+4j..+3)

  float acc[8][8];
  #pragma unroll
  for (int a0 = 0; a0 < 8; ++a0)
    #pragma unroll
    for (int b0 = 0; b0 < 8; ++b0) acc[a0][b0] = 0.f;

  const int ar = tid >> 2;            // 0..63 (t-row to load)
  const int aseg = (tid & 3) * 8;     // h sub-offset 0,8,16,24
  const int bh = tid >> 3;            // 0..31 (h-row of B chunk)
  const int bc = (tid & 7) * 32;      // 0..224 (c base, 32 cols)

  for (int kt = 0; kt < 96; ++kt) {
    const int delta = kt >> 5;          // conv tap 0..2
    const int h0 = (kt & 31) << 5;      // h chunk base

    float4 av0 = make_float4(0.f, 0.f, 0.f, 0.f), av1 = av0;
    const int tr = t0 + ar + delta - 1; // conv padding: zero outside [0,T)
    if (tr >= 0 && tr < T_LEN) {
      const float4* p = (const float4*)(x + (size_t)tr * H_DIM + h0 + aseg);
      av0 = p[0]; av1 = p[1];
    }
    const float4* q = (const float4*)(wt + ((size_t)delta * H_DIM + (h0 + bh)) * C_DIM + bc);
    float4 bv0 = q[0], bv1 = q[1], bv2 = q[2], bv3 = q[3],
           bv4 = q[4], bv5 = q[5], bv6 = q[6], bv7 = q[7];

    __syncthreads();   // previous iteration's readers done
    As[aseg + 0][ar] = av0.x; As[aseg + 1][ar] = av0.y;
    As[aseg + 2][ar] = av0.z; As[aseg + 3][ar] = av0.w;
    As[aseg + 4][ar] = av1.x; As[aseg + 5][ar] = av1.y;
    As[aseg + 6][ar] = av1.z; As[aseg + 7][ar] = av1.w;
    float4* bs = (float4*)&Bs[bh][bc];
    bs[0] = bv0; bs[1] = bv1; bs[2] = bv2; bs[3] = bv3;
    bs[4] = bv4; bs[5] = bv5; bs[6] = bv6; bs[7] = bv7;
    __syncthreads();

    #pragma unroll
    for (int k = 0; k < 32; ++k) {
      float a[8], b[8];
      *(float4*)&a[0] = *(const float4*)&As[k][8 * i];
      *(float4*)&a[4] = *(const float4*)&As[k][8 * i + 4];
      *(float4*)&b[0] = *(const float4*)&Bs[k][4 * j];
      *(float4*)&b[4] = *(const float4*)&Bs[k][128 + 4 * j];
      #pragma unroll
      for (int ii = 0; ii < 8; ++ii)
        #pragma unroll
        for (int qq = 0; qq < 8; ++qq)
          acc[ii][qq] = fmaf(a[ii], b[qq], acc[ii][qq]);
    }
  }

  // ---- epilogue: +bias, LN over C, ReLU, dot lin_w, sigmoid ----
  float g8[8], b8[8], w8[8], c8[8];
  #pragma unroll
  for (int qq = 0; qq < 8; ++qq) {
    int c = (qq < 4) ? (4 * j + qq) : (128 + 4 * j + (qq - 4));
    g8[qq] = lng[c]; b8[qq] = lnb[c]; w8[qq] = lw[c]; c8[qq] = cb[c];
  }
  const float lb0 = lb[0];
  #pragma unroll
  for (int ii = 0; ii < 8; ++ii) {
    float s = 0.f;
    #pragma unroll
    for (int qq = 0; qq < 8; ++qq) { acc[ii][qq] += c8[qq]; s += acc[ii][qq]; }
    #pragma unroll
    for (int m = 1; m < 32; m <<= 1) s += __shfl_xor(s, m, 64);
    const float mu = s * (1.0f / 256.0f);
    float ss = 0.f;
    #pragma unroll
    for (int qq = 0; qq < 8; ++qq) { float d = acc[ii][qq] - mu; ss += d * d; }
    #pragma unroll
    for (int m = 1; m < 32; m <<= 1) ss += __shfl_xor(ss, m, 64);
    const float var = ss * (1.0f / 256.0f);
    const float rstd = 1.0f / sqrtf(var + 1e-5f);
    float dot = 0.f;
    #pragma unroll
    for (int qq = 0; qq < 8; ++qq) {
      float v = (acc[ii][qq] - mu) * rstd * g8[qq] + b8[qq];
      v = fmaxf(v, 0.f);
      dot += v * w8[qq];
    }
    #pragma unroll
    for (int m = 1; m < 32; m <<= 1) dot += __shfl_xor(dot, m, 64);
    if (j == 0) {
      const float logit = dot + lb0;
      const float al = 1.0f / (1.0f + expf(-logit));
      alpha[t0 + 8 * i + ii] = al;
    }
  }
}

// exact-fp32 sequential CIF scan (matches jax op order bit-for-bit given alphas)
__global__ void kscan(const float* __restrict__ alpha, int* __restrict__ fire_t,
                      float* __restrict__ wu1, float* __restrict__ wu2,
                      int* __restrict__ meta, float* __restrict__ alphas_out)
{
  if (threadIdx.x != 0 || blockIdx.x != 0) return;
  float acc = 0.f;
  int nf = 0;
  double asum = 0.0;
  for (int t = 0; t < T_LEN; t += 8) {
    float av[8];
    #pragma unroll
    for (int u = 0; u < 8; ++u) av[u] = alpha[t + u];  // batched, latency-hidden
    #pragma unroll
    for (int u = 0; u < 8; ++u) {
      const float at = av[u];
      asum += (double)at;
      const float s = acc + at;          // fp32, same op order as reference
      const float au1 = 1.0f - acc;
      const float au2 = at - au1;
      if (s >= 1.0f) {
        fire_t[nf] = t + u; wu1[nf] = au1; wu2[nf] = au2;
        ++nf;
        acc = au2;
      } else {
        acc = s;
      }
    }
  }
  meta[0] = nf;
  meta[1] = (acc > 0.0f) ? 1 : 0;
  alphas_out[0] = (float)asum;
}

// per-output-row segmented weighted reduction over encoder rows
__global__ __launch_bounds__(256) void kscat(
    const float* __restrict__ x, const float* __restrict__ alpha,
    const int* __restrict__ fire_t, const float* __restrict__ wu1,
    const float* __restrict__ wu2, const int* __restrict__ meta,
    float* __restrict__ out)
{
  const int r = blockIdx.x;          // output row 0..T (16385 rows)
  const int tid = threadIdx.x;       // 4 floats each (H=1024)
  const int nf = meta[0];
  float4 acc = make_float4(0.f, 0.f, 0.f, 0.f);
  if (r < nf || (r == nf && meta[1])) {
    const bool isfin = (r == nf);
    const int tprev = (r > 0) ? fire_t[r - 1] : -1;
    const int tend = isfin ? (T_LEN - 1) : fire_t[r];
    const float wprev = (r > 0) ? wu2[r - 1] : 0.f;
    const float wlast = isfin ? 0.f : wu1[r];
    for (int t = (tprev < 0 ? 0 : tprev); t <= tend; ++t) {
      float w;
      if (!isfin && t == tend)      w = wlast;   // a_u1 at this row's fire
      else if (t == tprev)          w = wprev;   // a_u2 carried from prev fire
      else                          w = alpha[t];
      const float4 xv = ((const float4*)x)[(size_t)t * 256 + tid];
      acc.x = fmaf(w, xv.x, acc.x);
      acc.y = fmaf(w, xv.y, acc.y);
      acc.z = fmaf(w, xv.z, acc.z);
      acc.w = fmaf(w, xv.w, acc.w);
    }
  }
  ((float4*)out)[(size_t)r * 256 + tid] = acc;   // full overwrite (poison-safe)
}

extern "C" void kernel_launch(void* const* d_in, const int* in_sizes, int n_in,
                              void* d_out, int out_size, void* d_ws, size_t ws_size,
                              hipStream_t stream) {
  const float* enc   = (const float*)d_in[0];
  const float* convw = (const float*)d_in[1];
  const float* convb = (const float*)d_in[2];
  const float* lng   = (const float*)d_in[3];
  const float* lnb   = (const float*)d_in[4];
  const float* linw  = (const float*)d_in[5];
  const float* linb  = (const float*)d_in[6];
  float* out = (float*)d_out;

  float* ws     = (float*)d_ws;
  float* wt     = ws;                      // 786432 floats
  float* alpha  = ws + 786432;             // 16384
  int*   fire_t = (int*)(ws + 802816);     // 16384
  float* wu1    = ws + 819200;             // 16384
  float* wu2    = ws + 835584;             // 16384
  int*   meta   = (int*)(ws + 851968);     // 2

  hipLaunchKernelGGL(kwt,   dim3(1024),  dim3(256), 0, stream, convw, wt);
  hipLaunchKernelGGL(kconv, dim3(256),   dim3(256), 0, stream,
                     enc, wt, convb, lng, lnb, linw, linb, alpha);
  hipLaunchKernelGGL(kscan, dim3(1),     dim3(64),  0, stream,
                     alpha, fire_t, wu1, wu2, meta, out + (size_t)16385 * 1024);
  hipLaunchKernelGGL(kscat, dim3(16385), dim3(256), 0, stream,
                     enc, alpha, fire_t, wu1, wu2, meta, out);
}

// Round 3
// 1408.045 us; speedup vs baseline: 1.1472x; 1.1472x over previous
//
#include <hip/hip_runtime.h>
#include <math.h>

#define T_LEN 16384
#define H_DIM 1024
#define C_DIM 256

// ---------------- ws layout (float offsets) ----------------
// [0, 786432)       wt   : transposed weights (3, H, C)
// [786432, 802816)  alpha: (T)
// [802816, 819200)  fire_t (int)
// [819200, 835584)  wu1
// [835584, 851968)  wu2
// [851968, +8)      meta: nf (int), finflag (int)

// transpose conv_w (C,H,3) -> wt (3,H,C)  [coalesced writes]
__global__ __launch_bounds__(256) void kwt(const float* __restrict__ w,
                                           float* __restrict__ wt) {
  int idx = blockIdx.x * 256 + threadIdx.x;   // = h*256 + c
  int h = idx >> 8;
  int c = idx & 255;
  const float* s = w + ((size_t)c * H_DIM + h) * 3;
  float a0 = s[0], a1 = s[1], a2 = s[2];
  wt[((size_t)0 * H_DIM + h) * C_DIM + c] = a0;
  wt[((size_t)1 * H_DIM + h) * C_DIM + c] = a1;
  wt[((size_t)2 * H_DIM + h) * C_DIM + c] = a2;
}

// fused conv1d(K=3) + bias + LayerNorm + ReLU + linear + sigmoid -> alpha[T]
// BM=32 rows/block, 512 blocks -> 2 blocks/CU (2 waves/SIMD) for latency hiding.
__global__ __launch_bounds__(256) void kconv(
    const float* __restrict__ x, const float* __restrict__ wt,
    const float* __restrict__ cb, const float* __restrict__ lng,
    const float* __restrict__ lnb, const float* __restrict__ lw,
    const float* __restrict__ lb, float* __restrict__ alpha)
{
  __shared__ float As[32][36];    // [h_local][row], padded
  __shared__ float Bs[32][260];   // [h_local][col], padded
  const int tid = threadIdx.x;
  const int t0 = blockIdx.x * 32;
  const int i = tid >> 5;        // 0..7  row group (local rows 4i..4i+3)
  const int j = tid & 31;        // 0..31 col group (cols 4j..4j+3, 128+4j..+3)

  float acc[4][8];
  #pragma unroll
  for (int a0 = 0; a0 < 4; ++a0)
    #pragma unroll
    for (int b0 = 0; b0 < 8; ++b0) acc[a0][b0] = 0.f;

  const int ar = tid >> 3;            // 0..31 (t-row to load)
  const int aseg = (tid & 7) * 4;     // h sub-offset 0,4,...,28
  const int bh = tid >> 3;            // 0..31 (h-row of B chunk)
  const int bc = (tid & 7) * 32;      // 0..224 (c base, 32 cols)

  for (int kt = 0; kt < 96; ++kt) {
    const int delta = kt >> 5;          // conv tap 0..2
    const int h0 = (kt & 31) << 5;      // h chunk base

    float4 av = make_float4(0.f, 0.f, 0.f, 0.f);
    const int tr = t0 + ar + delta - 1; // conv padding: zero outside [0,T)
    if (tr >= 0 && tr < T_LEN)
      av = *(const float4*)(x + (size_t)tr * H_DIM + h0 + aseg);
    const float4* q = (const float4*)(wt + ((size_t)delta * H_DIM + (h0 + bh)) * C_DIM + bc);
    float4 bv0 = q[0], bv1 = q[1], bv2 = q[2], bv3 = q[3],
           bv4 = q[4], bv5 = q[5], bv6 = q[6], bv7 = q[7];

    __syncthreads();   // previous iteration's readers done
    As[aseg + 0][ar] = av.x; As[aseg + 1][ar] = av.y;
    As[aseg + 2][ar] = av.z; As[aseg + 3][ar] = av.w;
    float4* bs = (float4*)&Bs[bh][bc];
    bs[0] = bv0; bs[1] = bv1; bs[2] = bv2; bs[3] = bv3;
    bs[4] = bv4; bs[5] = bv5; bs[6] = bv6; bs[7] = bv7;
    __syncthreads();

    #pragma unroll
    for (int k = 0; k < 32; ++k) {
      float a[4], b[8];
      *(float4*)&a[0] = *(const float4*)&As[k][4 * i];
      *(float4*)&b[0] = *(const float4*)&Bs[k][4 * j];
      *(float4*)&b[4] = *(const float4*)&Bs[k][128 + 4 * j];
      #pragma unroll
      for (int ii = 0; ii < 4; ++ii)
        #pragma unroll
        for (int qq = 0; qq < 8; ++qq)
          acc[ii][qq] = fmaf(a[ii], b[qq], acc[ii][qq]);
    }
  }

  // ---- epilogue: +bias, LN over C, ReLU, dot lin_w, sigmoid ----
  float g8[8], b8[8], w8[8], c8[8];
  #pragma unroll
  for (int qq = 0; qq < 8; ++qq) {
    int c = (qq < 4) ? (4 * j + qq) : (128 + 4 * j + (qq - 4));
    g8[qq] = lng[c]; b8[qq] = lnb[c]; w8[qq] = lw[c]; c8[qq] = cb[c];
  }
  const float lb0 = lb[0];
  #pragma unroll
  for (int ii = 0; ii < 4; ++ii) {
    float s = 0.f;
    #pragma unroll
    for (int qq = 0; qq < 8; ++qq) { acc[ii][qq] += c8[qq]; s += acc[ii][qq]; }
    #pragma unroll
    for (int m = 1; m < 32; m <<= 1) s += __shfl_xor(s, m, 64);
    const float mu = s * (1.0f / 256.0f);
    float ss = 0.f;
    #pragma unroll
    for (int qq = 0; qq < 8; ++qq) { float d = acc[ii][qq] - mu; ss += d * d; }
    #pragma unroll
    for (int m = 1; m < 32; m <<= 1) ss += __shfl_xor(ss, m, 64);
    const float var = ss * (1.0f / 256.0f);
    const float rstd = 1.0f / sqrtf(var + 1e-5f);
    float dot = 0.f;
    #pragma unroll
    for (int qq = 0; qq < 8; ++qq) {
      float v = (acc[ii][qq] - mu) * rstd * g8[qq] + b8[qq];
      v = fmaxf(v, 0.f);
      dot += v * w8[qq];
    }
    #pragma unroll
    for (int m = 1; m < 32; m <<= 1) dot += __shfl_xor(dot, m, 64);
    if (j == 0) {
      const float logit = dot + lb0;
      const float al = 1.0f / (1.0f + expf(-logit));
      alpha[t0 + 4 * i + ii] = al;
    }
  }
}

// exact-fp32 sequential CIF scan, LDS-staged.
// 256 threads stage alpha (64 KB) into LDS; lane 0 runs the serial chain with
// 2-batch-ahead float4 prefetch (ds_read latency ~120cy hidden under ~96cy of
// chain work). Op order matches jax bit-for-bit: s=acc+a, au1=1-acc, au2=a-au1.
__global__ __launch_bounds__(256) void kscan(const float* __restrict__ alpha,
                      int* __restrict__ fire_t,
                      float* __restrict__ wu1, float* __restrict__ wu2,
                      int* __restrict__ meta, float* __restrict__ alphas_out)
{
  __shared__ float sa[T_LEN];   // 64 KB
  const int tid = threadIdx.x;
  #pragma unroll
  for (int b = 0; b < 16; ++b)
    ((float4*)sa)[b * 256 + tid] = ((const float4*)alpha)[b * 256 + tid];
  __syncthreads();
  if (tid != 0) return;

  float acc = 0.f;
  int nf = 0;
  double asum = 0.0;
  float4 c0 = *(const float4*)&sa[0];
  float4 c1 = *(const float4*)&sa[4];
  for (int t = 0; t < T_LEN; t += 4) {
    float4 nx = c1;
    if (t + 8 < T_LEN) nx = *(const float4*)&sa[t + 8];   // prefetch 2 ahead
    float av[4] = {c0.x, c0.y, c0.z, c0.w};
    #pragma unroll
    for (int u = 0; u < 4; ++u) {
      const float at = av[u];
      asum += (double)at;
      const float s = acc + at;          // fp32, same op order as reference
      const float au1 = 1.0f - acc;
      const float au2 = at - au1;
      if (s >= 1.0f) {
        fire_t[nf] = t + u; wu1[nf] = au1; wu2[nf] = au2;
        ++nf;
        acc = au2;
      } else {
        acc = s;
      }
    }
    c0 = c1; c1 = nx;
  }
  meta[0] = nf;
  meta[1] = (acc > 0.0f) ? 1 : 0;
  alphas_out[0] = (float)asum;
}

// per-output-row segmented weighted reduction over encoder rows
__global__ __launch_bounds__(256) void kscat(
    const float* __restrict__ x, const float* __restrict__ alpha,
    const int* __restrict__ fire_t, const float* __restrict__ wu1,
    const float* __restrict__ wu2, const int* __restrict__ meta,
    float* __restrict__ out)
{
  const int r = blockIdx.x;          // output row 0..T (16385 rows)
  const int tid = threadIdx.x;       // 4 floats each (H=1024)
  const int nf = meta[0];
  float4 acc = make_float4(0.f, 0.f, 0.f, 0.f);
  if (r < nf || (r == nf && meta[1])) {
    const bool isfin = (r == nf);
    const int tprev = (r > 0) ? fire_t[r - 1] : -1;
    const int tend = isfin ? (T_LEN - 1) : fire_t[r];
    const float wprev = (r > 0) ? wu2[r - 1] : 0.f;
    const float wlast = isfin ? 0.f : wu1[r];
    for (int t = (tprev < 0 ? 0 : tprev); t <= tend; ++t) {
      float w;
      if (!isfin && t == tend)      w = wlast;   // a_u1 at this row's fire
      else if (t == tprev)          w = wprev;   // a_u2 carried from prev fire
      else                          w = alpha[t];
      const float4 xv = ((const float4*)x)[(size_t)t * 256 + tid];
      acc.x = fmaf(w, xv.x, acc.x);
      acc.y = fmaf(w, xv.y, acc.y);
      acc.z = fmaf(w, xv.z, acc.z);
      acc.w = fmaf(w, xv.w, acc.w);
    }
  }
  ((float4*)out)[(size_t)r * 256 + tid] = acc;   // full overwrite (poison-safe)
}

extern "C" void kernel_launch(void* const* d_in, const int* in_sizes, int n_in,
                              void* d_out, int out_size, void* d_ws, size_t ws_size,
                              hipStream_t stream) {
  const float* enc   = (const float*)d_in[0];
  const float* convw = (const float*)d_in[1];
  const float* convb = (const float*)d_in[2];
  const float* lng   = (const float*)d_in[3];
  const float* lnb   = (const float*)d_in[4];
  const float* linw  = (const float*)d_in[5];
  const float* linb  = (const float*)d_in[6];
  float* out = (float*)d_out;

  float* ws     = (float*)d_ws;
  float* wt     = ws;                      // 786432 floats
  float* alpha  = ws + 786432;             // 16384
  int*   fire_t = (int*)(ws + 802816);     // 16384
  float* wu1    = ws + 819200;             // 16384
  float* wu2    = ws + 835584;             // 16384
  int*   meta   = (int*)(ws + 851968);     // 2

  hipLaunchKernelGGL(kwt,   dim3(1024),  dim3(256), 0, stream, convw, wt);
  hipLaunchKernelGGL(kconv, dim3(512),   dim3(256), 0, stream,
                     enc, wt, convb, lng, lnb, linw, linb, alpha);
  hipLaunchKernelGGL(kscan, dim3(1),     dim3(256), 0, stream,
                     alpha, fire_t, wu1, wu2, meta, out + (size_t)16385 * 1024);
  hipLaunchKernelGGL(kscat, dim3(16385), dim3(256), 0, stream,
                     enc, alpha, fire_t, wu1, wu2, meta, out);
}

// Round 4
// 856.270 us; speedup vs baseline: 1.8864x; 1.6444x over previous
//
#include <hip/hip_runtime.h>
#include <math.h>

#define T_LEN 16384
#define H_DIM 1024
#define C_DIM 256
#define BKC 16

// ---------------- ws layout (float offsets) ----------------
// [0, 786432)        wt    : transposed weights (3, H, C)
// [786432, 802816)   alpha : (T)
// [802816, 819200)   fire_t (int)
// [819200, 835584)   wu1
// [835584, 851968)   wu2
// [851968, 851976)   meta: nf (int), finflag (int)
// [851976, 868360)   atr  : acc trace (T)
// partial conv buffers live in d_out[0 .. 2*T*C) — kscat overwrites last.

// transpose conv_w (C,H,3) -> wt (3,H,C)  [coalesced writes]
__global__ __launch_bounds__(256) void kwt(const float* __restrict__ w,
                                           float* __restrict__ wt) {
  int idx = blockIdx.x * 256 + threadIdx.x;   // = h*256 + c
  int h = idx >> 8;
  int c = idx & 255;
  const float* s = w + ((size_t)c * H_DIM + h) * 3;
  float a0 = s[0], a1 = s[1], a2 = s[2];
  wt[((size_t)0 * H_DIM + h) * C_DIM + c] = a0;
  wt[((size_t)1 * H_DIM + h) * C_DIM + c] = a1;
  wt[((size_t)2 * H_DIM + h) * C_DIM + c] = a2;
}

// conv1d(K=3), 3-tap fused, 8x8 register blocking, split-K=2.
// grid 512: block = (tile = bx>>1 [64 t-rows], kh = bx&1 [512 h's]).
// Writes fp32 partial [kh][t][c] into scratch (d_out region).
__global__ __launch_bounds__(256) void kconv(
    const float* __restrict__ x, const float* __restrict__ wt,
    float* __restrict__ part)
{
  __shared__ float As[BKC][68];      // [h_local][t_local 0..65] (66 rows = 64 + halo)
  __shared__ float Bs[3][BKC][256];  // [tap][h_local][c]
  const int tid  = threadIdx.x;
  const int tile = blockIdx.x >> 1;
  const int kh   = blockIdx.x & 1;
  const int t0   = tile * 64;
  const int i = tid >> 5;        // 0..7  row group (rows 8i..8i+7)
  const int j = tid & 31;        // 0..31 col group (cols 4j.., 128+4j..)

  float acc[8][8];
  #pragma unroll
  for (int a0 = 0; a0 < 8; ++a0)
    #pragma unroll
    for (int b0 = 0; b0 < 8; ++b0) acc[a0][b0] = 0.f;

  const int tloc = tid >> 2;          // 0..63 A-stage row
  const int hg   = tid & 3;           // h sub-group (4 h per float4)

  for (int kt = 0; kt < 32; ++kt) {
    const int h0 = kh * 512 + kt * BKC;

    // ---- global loads into regs (B: 12 float4; A: 1 + tail) ----
    float4 breg[12];
    #pragma unroll
    for (int it = 0; it < 12; ++it) {
      const int task = tid + it * 256;     // 0..3071
      const int dl  = task >> 10;          // tap 0..2
      const int rem = task & 1023;
      const int kk  = rem >> 6;            // 0..15
      const int cg  = rem & 63;            // col group
      breg[it] = *(const float4*)(wt + ((size_t)dl * H_DIM + h0 + kk) * C_DIM + 4 * cg);
    }
    float4 areg0 = make_float4(0.f, 0.f, 0.f, 0.f), areg1 = areg0;
    {
      const int tr = t0 + tloc - 1;                       // halo: row t0-1
      if (tr >= 0 && tr < T_LEN)
        areg0 = *(const float4*)(x + (size_t)tr * H_DIM + h0 + 4 * hg);
      if (tid < 8) {                                      // rows 64,65 of the 66
        const int tl2 = 64 + (tid >> 2);
        const int tr2 = t0 + tl2 - 1;
        if (tr2 >= 0 && tr2 < T_LEN)
          areg1 = *(const float4*)(x + (size_t)tr2 * H_DIM + h0 + 4 * (tid & 3));
      }
    }
    __syncthreads();   // previous iteration's readers done
    #pragma unroll
    for (int it = 0; it < 12; ++it) {
      const int task = tid + it * 256;
      const int dl  = task >> 10;
      const int rem = task & 1023;
      const int kk  = rem >> 6;
      const int cg  = rem & 63;
      *(float4*)&Bs[dl][kk][4 * cg] = breg[it];
    }
    As[4 * hg + 0][tloc] = areg0.x; As[4 * hg + 1][tloc] = areg0.y;
    As[4 * hg + 2][tloc] = areg0.z; As[4 * hg + 3][tloc] = areg0.w;
    if (tid < 8) {
      const int tl2 = 64 + (tid >> 2), hg2 = (tid & 3) * 4;
      As[hg2 + 0][tl2] = areg1.x; As[hg2 + 1][tl2] = areg1.y;
      As[hg2 + 2][tl2] = areg1.z; As[hg2 + 3][tl2] = areg1.w;
    }
    __syncthreads();

    #pragma unroll
    for (int k = 0; k < BKC; ++k) {
      float aw[10];
      *(float4*)&aw[0] = *(const float4*)&As[k][8 * i];
      *(float4*)&aw[4] = *(const float4*)&As[k][8 * i + 4];
      *(float2*)&aw[8] = *(const float2*)&As[k][8 * i + 8];
      float bw[3][8];
      #pragma unroll
      for (int dl = 0; dl < 3; ++dl) {
        *(float4*)&bw[dl][0] = *(const float4*)&Bs[dl][k][4 * j];
        *(float4*)&bw[dl][4] = *(const float4*)&Bs[dl][k][128 + 4 * j];
      }
      // out row r=8i+ii, tap dl uses x row (r+dl-1) -> window index ii+dl
      #pragma unroll
      for (int ii = 0; ii < 8; ++ii)
        #pragma unroll
        for (int qq = 0; qq < 8; ++qq)
          acc[ii][qq] = fmaf(aw[ii],     bw[0][qq],
                        fmaf(aw[ii + 1], bw[1][qq],
                        fmaf(aw[ii + 2], bw[2][qq], acc[ii][qq])));
    }
  }

  float* p = part + (size_t)kh * T_LEN * C_DIM;
  #pragma unroll
  for (int ii = 0; ii < 8; ++ii) {
    const size_t t = t0 + 8 * i + ii;
    *(float4*)&p[t * C_DIM + 4 * j]       = make_float4(acc[ii][0], acc[ii][1], acc[ii][2], acc[ii][3]);
    *(float4*)&p[t * C_DIM + 128 + 4 * j] = make_float4(acc[ii][4], acc[ii][5], acc[ii][6], acc[ii][7]);
  }
}

// combine split-K partials + bias + LN + ReLU + linear + sigmoid -> alpha[t]
// one wave per t-row.
__global__ __launch_bounds__(64) void kadd(
    const float* __restrict__ part, const float* __restrict__ cb,
    const float* __restrict__ lng, const float* __restrict__ lnb,
    const float* __restrict__ lw, const float* __restrict__ lb,
    float* __restrict__ alpha)
{
  const int row = blockIdx.x;
  const int l = threadIdx.x;            // 0..63, cols 4l..4l+3
  const float4 p0 = *(const float4*)&part[(size_t)row * C_DIM + 4 * l];
  const float4 p1 = *(const float4*)&part[(size_t)T_LEN * C_DIM + (size_t)row * C_DIM + 4 * l];
  const float4 cb4 = *(const float4*)&cb[4 * l];
  float v[4] = {p0.x + p1.x + cb4.x, p0.y + p1.y + cb4.y,
                p0.z + p1.z + cb4.z, p0.w + p1.w + cb4.w};
  float s = v[0] + v[1] + v[2] + v[3];
  #pragma unroll
  for (int m = 1; m < 64; m <<= 1) s += __shfl_xor(s, m, 64);
  const float mu = s * (1.0f / 256.0f);
  float ss = 0.f;
  #pragma unroll
  for (int q = 0; q < 4; ++q) { const float d = v[q] - mu; ss += d * d; }
  #pragma unroll
  for (int m = 1; m < 64; m <<= 1) ss += __shfl_xor(ss, m, 64);
  const float rstd = 1.0f / sqrtf(ss * (1.0f / 256.0f) + 1e-5f);
  const float4 g4 = *(const float4*)&lng[4 * l];
  const float4 b4 = *(const float4*)&lnb[4 * l];
  const float4 w4 = *(const float4*)&lw[4 * l];
  const float gg[4] = {g4.x, g4.y, g4.z, g4.w};
  const float bb[4] = {b4.x, b4.y, b4.z, b4.w};
  const float ww[4] = {w4.x, w4.y, w4.z, w4.w};
  float dot = 0.f;
  #pragma unroll
  for (int q = 0; q < 4; ++q) {
    float h = (v[q] - mu) * rstd * gg[q] + bb[q];
    h = fmaxf(h, 0.f);
    dot = fmaf(h, ww[q], dot);
  }
  #pragma unroll
  for (int m = 1; m < 64; m <<= 1) dot += __shfl_xor(dot, m, 64);
  if (l == 0)
    alpha[row] = 1.0f / (1.0f + expf(-(dot + lb[0])));
}

// exact-fp32 serial CIF chain: branch-free, minimal (6 VALU/elem).
// Stores only the acc trace; fires/compaction recomputed in kscan2.
__global__ __launch_bounds__(256) void kscan(const float* __restrict__ alpha,
                                             float* __restrict__ atr)
{
  __shared__ float sa[T_LEN];   // 64 KB
  const int tid = threadIdx.x;
  #pragma unroll
  for (int b = 0; b < 16; ++b)
    ((float4*)sa)[b * 256 + tid] = ((const float4*)alpha)[b * 256 + tid];
  __syncthreads();
  if (tid != 0) return;

  const float4* sa4 = (const float4*)sa;
  float acc = 0.f;
  float4 c0 = sa4[0], c1 = sa4[1], c2 = sa4[2], c3 = sa4[3];
  for (int t = 0; t < T_LEN; t += 8) {
    const int nid = (t + 16 < T_LEN) ? ((t >> 2) + 4) : (t >> 2);
    const float4 n0 = sa4[nid], n1 = sa4[nid + 1];
    const float av[8] = {c0.x, c0.y, c0.z, c0.w, c1.x, c1.y, c1.z, c1.w};
    float tr[8];
    #pragma unroll
    for (int u = 0; u < 8; ++u) {
      const float at  = av[u];
      const float s   = acc + at;        // fp32, reference op order
      const float au1 = 1.0f - acc;
      const float au2 = at - au1;
      acc = (s >= 1.0f) ? au2 : s;       // v_cmp + v_cndmask, no branch
      tr[u] = acc;
    }
    *(float4*)&atr[t]     = make_float4(tr[0], tr[1], tr[2], tr[3]);
    *(float4*)&atr[t + 4] = make_float4(tr[4], tr[5], tr[6], tr[7]);
    c0 = c2; c1 = c3; c2 = n0; c3 = n1;
  }
}

// parallel fire extraction + compaction + alpha sum.
// fire decision recomputed from trace: bit-identical to kscan's
// (same fp32 ops on same inputs).
__global__ __launch_bounds__(256) void kscan2(
    const float* __restrict__ alpha, const float* __restrict__ atr,
    int* __restrict__ fire_t, float* __restrict__ wu1, float* __restrict__ wu2,
    int* __restrict__ meta, float* __restrict__ alphas_out)
{
  __shared__ int wsum[4];
  const int tid = threadIdx.x;
  const int lane = tid & 63, wv = tid >> 6;
  int gbase = 0;
  float asum = 0.f;
  for (int it = 0; it < 64; ++it) {
    const int t = it * 256 + tid;
    const float at = alpha[t];
    asum += at;
    const float prev = (t == 0) ? 0.f : atr[t - 1];
    const float s = prev + at;
    const bool fire = (s >= 1.0f);
    const unsigned long long m = __ballot(fire);
    const int lpre = __popcll(m & ((1ull << lane) - 1ull));
    if (lane == 0) wsum[wv] = __popcll(m);
    __syncthreads();
    int wpre = 0, total = 0;
    #pragma unroll
    for (int w = 0; w < 4; ++w) {
      if (w < wv) wpre += wsum[w];
      total += wsum[w];
    }
    if (fire) {
      const int idx = gbase + wpre + lpre;
      fire_t[idx] = t;
      const float au1 = 1.0f - prev;
      wu1[idx] = au1;
      wu2[idx] = at - au1;
    }
    gbase += total;
    __syncthreads();   // protect wsum reuse
  }
  #pragma unroll
  for (int m2 = 1; m2 < 64; m2 <<= 1) asum += __shfl_xor(asum, m2, 64);
  __shared__ float fsum[4];
  if (lane == 0) fsum[wv] = asum;
  __syncthreads();
  if (tid == 0) {
    alphas_out[0] = fsum[0] + fsum[1] + fsum[2] + fsum[3];
    meta[0] = gbase;
    meta[1] = (atr[T_LEN - 1] > 0.0f) ? 1 : 0;
  }
}

// per-output-row segmented weighted reduction over encoder rows
__global__ __launch_bounds__(256) void kscat(
    const float* __restrict__ x, const float* __restrict__ alpha,
    const int* __restrict__ fire_t, const float* __restrict__ wu1,
    const float* __restrict__ wu2, const int* __restrict__ meta,
    float* __restrict__ out)
{
  const int r = blockIdx.x;          // output row 0..T (16385 rows)
  const int tid = threadIdx.x;       // 4 floats each (H=1024)
  const int nf = meta[0];
  float4 acc = make_float4(0.f, 0.f, 0.f, 0.f);
  if (r < nf || (r == nf && meta[1])) {
    const bool isfin = (r == nf);
    const int tprev = (r > 0) ? fire_t[r - 1] : -1;
    const int tend = isfin ? (T_LEN - 1) : fire_t[r];
    const float wprev = (r > 0) ? wu2[r - 1] : 0.f;
    const float wlast = isfin ? 0.f : wu1[r];
    for (int t = (tprev < 0 ? 0 : tprev); t <= tend; ++t) {
      float w;
      if (!isfin && t == tend)      w = wlast;   // a_u1 at this row's fire
      else if (t == tprev)          w = wprev;   // a_u2 carried from prev fire
      else                          w = alpha[t];
      const float4 xv = ((const float4*)x)[(size_t)t * 256 + tid];
      acc.x = fmaf(w, xv.x, acc.x);
      acc.y = fmaf(w, xv.y, acc.y);
      acc.z = fmaf(w, xv.z, acc.z);
      acc.w = fmaf(w, xv.w, acc.w);
    }
  }
  ((float4*)out)[(size_t)r * 256 + tid] = acc;   // full overwrite (poison-safe)
}

extern "C" void kernel_launch(void* const* d_in, const int* in_sizes, int n_in,
                              void* d_out, int out_size, void* d_ws, size_t ws_size,
                              hipStream_t stream) {
  const float* enc   = (const float*)d_in[0];
  const float* convw = (const float*)d_in[1];
  const float* convb = (const float*)d_in[2];
  const float* lng   = (const float*)d_in[3];
  const float* lnb   = (const float*)d_in[4];
  const float* linw  = (const float*)d_in[5];
  const float* linb  = (const float*)d_in[6];
  float* out = (float*)d_out;

  float* ws     = (float*)d_ws;
  float* wt     = ws;                      // 786432 floats
  float* alpha  = ws + 786432;             // 16384
  int*   fire_t = (int*)(ws + 802816);     // 16384
  float* wu1    = ws + 819200;             // 16384
  float* wu2    = ws + 835584;             // 16384
  int*   meta   = (int*)(ws + 851968);     // 2
  float* atr    = ws + 851976;             // 16384 (acc trace)

  float* part = out;                       // 2 x T x C scratch in d_out; kscat overwrites last

  hipLaunchKernelGGL(kwt,    dim3(1024),  dim3(256), 0, stream, convw, wt);
  hipLaunchKernelGGL(kconv,  dim3(512),   dim3(256), 0, stream, enc, wt, part);
  hipLaunchKernelGGL(kadd,   dim3(16384), dim3(64),  0, stream,
                     part, convb, lng, lnb, linw, linb, alpha);
  hipLaunchKernelGGL(kscan,  dim3(1),     dim3(256), 0, stream, alpha, atr);
  hipLaunchKernelGGL(kscan2, dim3(1),     dim3(256), 0, stream,
                     alpha, atr, fire_t, wu1, wu2, meta, out + (size_t)16385 * 1024);
  hipLaunchKernelGGL(kscat,  dim3(16385), dim3(256), 0, stream,
                     enc, alpha, fire_t, wu1, wu2, meta, out);
}